// Round 19
// baseline (166.040 us; speedup 1.0000x reference)
//
#include <hip/hip_runtime.h>

// Neural-ODE, f(y) = tanh(y@W1+b1)@W2 + b2, 20800 independent 64-dim points.
// R19 = R18 with three independent levers:
//  1. SEG_CAP 0.20 -> 0.25 (fevals/wave ~26 -> ~21; absmax was pinned at the
//     1-ulp bf16 floor for 0.15 AND 0.20, so truncation has >=3x headroom).
//  2. feval critical path: layer-1 2-chain -> 2 parallel MFMAs + add;
//     layer-2 4-chain -> 2x2-chain + add (serial MFMA latencies 6 -> 3).
//  3. kernel2: compute phase unchanged (lane=dim, cached per-segment regs),
//     but results staged to LDS ybuf and stored as 6 contiguous float4/lane
//     (1 KB/wave-instruction, fully coalesced).
// Structure (R15-R18 proven): spill-free rolled-RK4 recorder (kernel1) +
// Hermite expander (kernel2); f16 records {y0,f0} per segment in ws.
// Per-feval machinery R8-R10-verified (zero-shuffle pi-permuted MFMA).

#define NB 64
#define NPT 325
#define ND 64
#define NH 128
#define NTOUT 24
#define GP16 21                   // ceil(325/16)
#define NTASK (NB * GP16)         // 1344 single-wave blocks
#define SEG_CAP 0.25f             // max RK4 step span (dt in [0.01,0.1])
#define CHUNK 4
#define NCHUNK ((NPT + CHUNK - 1) / CHUNK)   // 82

using f16x8 = __attribute__((ext_vector_type(8))) _Float16;
using f16x2 = __attribute__((ext_vector_type(2))) _Float16;
using f32x4 = __attribute__((ext_vector_type(4))) float;
using u32x4 = __attribute__((ext_vector_type(4))) unsigned;

__device__ __forceinline__ unsigned pack2(float lo, float hi) {
  auto pk = __builtin_amdgcn_cvt_pkrtz(lo, hi);
  return __builtin_bit_cast(unsigned, pk);
}

__device__ __forceinline__ f16x8 frag4(unsigned a, unsigned b, unsigned c, unsigned d) {
  u32x4 u = {a, b, c, d};
  return __builtin_bit_cast(f16x8, u);
}

__device__ __forceinline__ float h16(unsigned u, int hi) {
  f16x2 h = __builtin_bit_cast(f16x2, u);
  return (float)h[hi];
}

// ============================ kernel 1 ======================================
__global__ __launch_bounds__(64, 2) void node_rec_kernel(
    const float* __restrict__ y0g, const float* __restrict__ tsg,
    const float* __restrict__ W1g, const float* __restrict__ b1g,
    const float* __restrict__ W2g, const float* __restrict__ b2g,
    unsigned* __restrict__ wsu) {
  const int lane = threadIdx.x & 63;
  const int c = lane & 15;
  const int g = lane >> 4;

  const int task = blockIdx.x;
  const int b = task / GP16;
  const int p0 = (task - b * GP16) * 16;

  const float SC = 2.885390081777927f;  // 2*log2(e), folded into W1/b1

  f16x8 wf1[8][2];
#pragma unroll
  for (int rt = 0; rt < 8; ++rt)
#pragma unroll
    for (int kt = 0; kt < 2; ++kt) {
      f16x8 a;
#pragma unroll
      for (int j = 0; j < 8; ++j) {
        int ek = 4 * g + (j & 3) + ((j >> 2) << 4);
        a[j] = (_Float16)(W1g[(32 * kt + ek) * NH + 16 * rt + c] * SC);
      }
      wf1[rt][kt] = a;
    }
  f16x8 wf2[4][4];
#pragma unroll
  for (int rt = 0; rt < 4; ++rt)
#pragma unroll
    for (int kt = 0; kt < 4; ++kt) {
      f16x8 a;
#pragma unroll
      for (int j = 0; j < 8; ++j) {
        int ek = 4 * g + (j & 3) + ((j >> 2) << 4);
        a[j] = (_Float16)W2g[(32 * kt + ek) * ND + 16 * rt + c];
      }
      wf2[rt][kt] = a;
    }

  f32x4 b1C[8], b2C[4];
#pragma unroll
  for (int rt = 0; rt < 8; ++rt)
#pragma unroll
    for (int q = 0; q < 4; ++q) b1C[rt][q] = b1g[16 * rt + 4 * g + q] * SC;
#pragma unroll
  for (int rt = 0; rt < 4; ++rt)
#pragma unroll
    for (int q = 0; q < 4; ++q) b2C[rt][q] = b2g[16 * rt + 4 * g + q];

  const int ptc = p0 + c;
  const int qpt = b * NPT + min(ptc, NPT - 1);
  // clamped lanes duplicate the last point bitwise-identically (benign dups)

  float y[16], y5[16];
#pragma unroll
  for (int mt = 0; mt < 4; ++mt) {
    float4 v = *(const float4*)&y0g[qpt * ND + 16 * mt + 4 * g];
    y[4 * mt + 0] = v.x; y[4 * mt + 1] = v.y;
    y[4 * mt + 2] = v.z; y[4 * mt + 3] = v.w;
  }

  f16x8 yb0, yb1;
  auto mkyb = [&](const float* v) {
    yb0 = frag4(pack2(v[0], v[1]), pack2(v[2], v[3]),
                pack2(v[4], v[5]), pack2(v[6], v[7]));
    yb1 = frag4(pack2(v[8], v[9]), pack2(v[10], v[11]),
                pack2(v[12], v[13]), pack2(v[14], v[15]));
  };

  const f32x4 zf = {0.0f, 0.0f, 0.0f, 0.0f};
  f32x4 acc2[4];
  auto feval = [&]() {
    // layer 1: two INDEPENDENT MFMAs per row-tile + f32 add (1 MFMA latency)
    f32x4 acc[8];
#pragma unroll
    for (int rt = 0; rt < 8; ++rt) {
      f32x4 tA = __builtin_amdgcn_mfma_f32_16x16x32_f16(wf1[rt][0], yb0, b1C[rt], 0, 0, 0);
      f32x4 tB = __builtin_amdgcn_mfma_f32_16x16x32_f16(wf1[rt][1], yb1, zf, 0, 0, 0);
      acc[rt] = tA + tB;
    }
    float th[32];
#pragma unroll
    for (int i = 0; i < 32; ++i) th[i] = __builtin_exp2f(acc[i >> 2][i & 3]);
#pragma unroll
    for (int i = 0; i < 32; ++i) th[i] = __builtin_amdgcn_rcpf(th[i] + 1.0f);
    f16x8 hb[4];
#pragma unroll
    for (int kt = 0; kt < 4; ++kt) {
      hb[kt] = frag4(
          pack2(fmaf(-2.0f, th[8 * kt + 0], 1.0f), fmaf(-2.0f, th[8 * kt + 1], 1.0f)),
          pack2(fmaf(-2.0f, th[8 * kt + 2], 1.0f), fmaf(-2.0f, th[8 * kt + 3], 1.0f)),
          pack2(fmaf(-2.0f, th[8 * kt + 4], 1.0f), fmaf(-2.0f, th[8 * kt + 5], 1.0f)),
          pack2(fmaf(-2.0f, th[8 * kt + 6], 1.0f), fmaf(-2.0f, th[8 * kt + 7], 1.0f)));
    }
    // layer 2: 2x2-chain + add (2 MFMA latencies instead of 4)
#pragma unroll
    for (int rt = 0; rt < 4; ++rt) {
      f32x4 tA = __builtin_amdgcn_mfma_f32_16x16x32_f16(wf2[rt][0], hb[0], b2C[rt], 0, 0, 0);
      tA = __builtin_amdgcn_mfma_f32_16x16x32_f16(wf2[rt][1], hb[1], tA, 0, 0, 0);
      f32x4 tB = __builtin_amdgcn_mfma_f32_16x16x32_f16(wf2[rt][2], hb[2], zf, 0, 0, 0);
      tB = __builtin_amdgcn_mfma_f32_16x16x32_f16(wf2[rt][3], hb[3], tB, 0, 0, 0);
      acc2[rt] = tA + tB;
    }
  };

#define FV(i) (acc2[(i) >> 2][(i) & 3])

  const unsigned rbase = (unsigned)qpt * 1536u;
  auto store_rec = [&](int s) {  // record = {y0[64] f16, f0[64] f16}
    const unsigned o = rbase + (unsigned)s * 64u + 2u * g;
#pragma unroll
    for (int mt = 0; mt < 4; ++mt) {
      uint2 uy = make_uint2(pack2(y[4 * mt], y[4 * mt + 1]),
                            pack2(y[4 * mt + 2], y[4 * mt + 3]));
      *(uint2*)&wsu[o + 8u * mt] = uy;
      uint2 uf = make_uint2(pack2(FV(4 * mt), FV(4 * mt + 1)),
                            pack2(FV(4 * mt + 2), FV(4 * mt + 3)));
      *(uint2*)&wsu[o + 32u + 8u * mt] = uf;
    }
  };

  float t0 = tsg[b];
  mkyb(y);

  int s = 0;
  int k = 1;
#pragma unroll 1
  while (k < NTOUT) {
    int kend = k;
    float tend = tsg[k * NB + b];
#pragma unroll 1
    while (kend + 1 < NTOUT) {
      float tn = tsg[(kend + 1) * NB + b];
      if (tn - t0 <= SEG_CAP) { kend = kend + 1; tend = tn; } else break;
    }
    const float H = tend - t0;
    const float H2 = 0.5f * H;
    const float H6 = H * (1.0f / 6.0f);
    const float H3 = 2.0f * H6;

#pragma unroll
    for (int i = 0; i < 16; ++i) y5[i] = y[i];

#pragma unroll 1
    for (int st = 0; st < 4; ++st) {  // rolled stage loop (spill-free shape)
      feval();
      if (st == 0) store_rec(s);  // uniform branch: {y0, k1}
      const float cB = (st == 0 || st == 3) ? H6 : H3;
#pragma unroll
      for (int i = 0; i < 16; ++i) y5[i] = fmaf(cB, FV(i), y5[i]);
      if (st < 3) {
        const float cA = (st == 2) ? H : H2;
        float yt[16];
#pragma unroll
        for (int i = 0; i < 16; ++i) yt[i] = fmaf(cA, FV(i), y[i]);
        mkyb(yt);
      } else {
#pragma unroll
        for (int i = 0; i < 16; ++i) y[i] = y5[i];
        mkyb(y);
      }
    }
    s++;
    t0 = tend;
    k = kend + 1;
  }
  feval();
  store_rec(s);  // final {y_end, f_end}
#undef FV
}

// ============================ kernel 2 ======================================
// Block = 4 points of one batch; wave = point, lane = dim d for compute;
// results staged in LDS ybuf, then stored as contiguous float4 runs.
__global__ __launch_bounds__(256) void hermite_out_kernel(
    const float* __restrict__ y0g, const float* __restrict__ tsg,
    const unsigned* __restrict__ wsu, float* __restrict__ outg) {
  __shared__ float ts_s[NTOUT];
  __shared__ float c0s[NTOUT], c1s[NTOUT], c2s[NTOUT], c3s[NTOUT];
  __shared__ int sidx[NTOUT];
  __shared__ int nseg_s;
  __shared__ unsigned recs[CHUNK][NTOUT * 64];   // 24 KB
  __shared__ float ybuf[CHUNK][ND][NTOUT + 1];   // 25.6 KB (pad 25)

  const int tid = threadIdx.x;
  const int b = blockIdx.x / NCHUNK;
  const int chunk = blockIdx.x - b * NCHUNK;
  const int pbase = chunk * CHUNK;

  if (tid < NTOUT) ts_s[tid] = tsg[tid * NB + b];
  __syncthreads();

  if (tid == 0) {  // identical FP logic to kernel1's merge
    float t0 = ts_s[0];
    int s = 0, k = 1;
    while (k < NTOUT) {
      int kend = k;
      float tend = ts_s[k];
      while (kend + 1 < NTOUT) {
        float tn = ts_s[kend + 1];
        if (tn - t0 <= SEG_CAP) { kend = kend + 1; tend = tn; } else break;
      }
      float H = tend - t0;
      for (int kk = k; kk <= kend; ++kk) {
        float th = (ts_s[kk] - t0) / H;
        float th2 = th * th, th3 = th2 * th;
        c0s[kk] = 2.0f * th3 - 3.0f * th2 + 1.0f;
        c1s[kk] = (th3 - 2.0f * th2 + th) * H;
        c2s[kk] = 3.0f * th2 - 2.0f * th3;
        c3s[kk] = (th3 - th2) * H;
        sidx[kk] = s;
      }
      s++;
      t0 = tend;
      k = kend + 1;
    }
    nseg_s = s;
  }
  __syncthreads();

  // stage records for the 4 points (coalesced uint4 loads, linear LDS)
  const int nr4 = (nseg_s + 1) * 16;  // uint4 per point
#pragma unroll 1
  for (int p = 0; p < CHUNK; ++p) {
    const int q = b * NPT + min(pbase + p, NPT - 1);
    const u32x4* src = (const u32x4*)(wsu + (size_t)q * 1536u);
#pragma unroll 1
    for (int i = tid; i < nr4; i += 256)
      *(u32x4*)&recs[p][i * 4] = src[i];
  }
  __syncthreads();

  // compute phase: wave w = point pbase+w, lane = dim d
  const int w = tid >> 6;
  const int lane = tid & 63;
  const int pt = pbase + w;
  const bool valid = pt < NPT;
  const int q = b * NPT + min(pt, NPT - 1);
  const int dw = lane >> 1, hi = lane & 1;

  ybuf[w][lane][0] = y0g[q * ND + lane];  // exact k=0

  float y0v = 0.f, f0v = 0.f, y1v = 0.f, f1v = 0.f;
  int cur = -1;
#pragma unroll 1
  for (int k = 1; k < NTOUT; ++k) {
    const int s = sidx[k];     // uniform across wave
    if (s != cur) {            // uniform branch; ~6 reloads per point
      cur = s;
      y0v = h16(recs[w][s * 64 + dw], hi);
      f0v = h16(recs[w][s * 64 + 32 + dw], hi);
      y1v = h16(recs[w][(s + 1) * 64 + dw], hi);
      f1v = h16(recs[w][(s + 1) * 64 + 32 + dw], hi);
    }
    ybuf[w][lane][k] = fmaf(c0s[k], y0v,
                       fmaf(c1s[k], f0v,
                       fmaf(c2s[k], y1v, c3s[k] * f1v)));
  }
  // store phase: same wave reads its own ybuf (in-wave LDS ordering) and
  // writes 6 contiguous float4 runs (1 KB per wave-instruction, coalesced)
  if (valid) {
    float* obase = outg + (size_t)q * (ND * NTOUT);
#pragma unroll 1
    for (int it = 0; it < 6; ++it) {
      const int f = it * 256 + lane * 4;
      float4 v;
      v.x = ybuf[w][(f + 0) / NTOUT][(f + 0) % NTOUT];
      v.y = ybuf[w][(f + 1) / NTOUT][(f + 1) % NTOUT];
      v.z = ybuf[w][(f + 2) / NTOUT][(f + 2) % NTOUT];
      v.w = ybuf[w][(f + 3) / NTOUT][(f + 3) % NTOUT];
      *(float4*)&obase[f] = v;
    }
  }
}

// ====================== fallback (ws too small; never expected) =============
__global__ __launch_bounds__(64, 2) void node_direct_kernel(
    const float* __restrict__ y0g, const float* __restrict__ tsg,
    const float* __restrict__ W1g, const float* __restrict__ b1g,
    const float* __restrict__ W2g, const float* __restrict__ b2g,
    float* __restrict__ outg) {
  const int lane = threadIdx.x & 63;
  const int c = lane & 15;
  const int g = lane >> 4;
  const int task = blockIdx.x;
  const int b = task / GP16;
  const int p0 = (task - b * GP16) * 16;
  const float SC = 2.885390081777927f;

  f16x8 wf1[8][2];
#pragma unroll
  for (int rt = 0; rt < 8; ++rt)
#pragma unroll
    for (int kt = 0; kt < 2; ++kt) {
      f16x8 a;
#pragma unroll
      for (int j = 0; j < 8; ++j) {
        int ek = 4 * g + (j & 3) + ((j >> 2) << 4);
        a[j] = (_Float16)(W1g[(32 * kt + ek) * NH + 16 * rt + c] * SC);
      }
      wf1[rt][kt] = a;
    }
  f16x8 wf2[4][4];
#pragma unroll
  for (int rt = 0; rt < 4; ++rt)
#pragma unroll
    for (int kt = 0; kt < 4; ++kt) {
      f16x8 a;
#pragma unroll
      for (int j = 0; j < 8; ++j) {
        int ek = 4 * g + (j & 3) + ((j >> 2) << 4);
        a[j] = (_Float16)W2g[(32 * kt + ek) * ND + 16 * rt + c];
      }
      wf2[rt][kt] = a;
    }
  f32x4 b1C[8], b2C[4];
#pragma unroll
  for (int rt = 0; rt < 8; ++rt)
#pragma unroll
    for (int q = 0; q < 4; ++q) b1C[rt][q] = b1g[16 * rt + 4 * g + q] * SC;
#pragma unroll
  for (int rt = 0; rt < 4; ++rt)
#pragma unroll
    for (int q = 0; q < 4; ++q) b2C[rt][q] = b2g[16 * rt + 4 * g + q];

  const int ptc = p0 + c;
  const bool valid = ptc < NPT;
  const int qpt = b * NPT + min(ptc, NPT - 1);
  float y[16], y5[16];
#pragma unroll
  for (int mt = 0; mt < 4; ++mt) {
    float4 v = *(const float4*)&y0g[qpt * ND + 16 * mt + 4 * g];
    y[4 * mt + 0] = v.x; y[4 * mt + 1] = v.y;
    y[4 * mt + 2] = v.z; y[4 * mt + 3] = v.w;
  }
  f16x8 yb0, yb1;
  auto mkyb = [&](const float* v) {
    yb0 = frag4(pack2(v[0], v[1]), pack2(v[2], v[3]),
                pack2(v[4], v[5]), pack2(v[6], v[7]));
    yb1 = frag4(pack2(v[8], v[9]), pack2(v[10], v[11]),
                pack2(v[12], v[13]), pack2(v[14], v[15]));
  };
  const f32x4 zf = {0.0f, 0.0f, 0.0f, 0.0f};
  f32x4 acc2[4];
  auto feval = [&]() {
    f32x4 acc[8];
#pragma unroll
    for (int rt = 0; rt < 8; ++rt) {
      f32x4 tA = __builtin_amdgcn_mfma_f32_16x16x32_f16(wf1[rt][0], yb0, b1C[rt], 0, 0, 0);
      f32x4 tB = __builtin_amdgcn_mfma_f32_16x16x32_f16(wf1[rt][1], yb1, zf, 0, 0, 0);
      acc[rt] = tA + tB;
    }
    float th[32];
#pragma unroll
    for (int i = 0; i < 32; ++i) th[i] = __builtin_exp2f(acc[i >> 2][i & 3]);
#pragma unroll
    for (int i = 0; i < 32; ++i) th[i] = __builtin_amdgcn_rcpf(th[i] + 1.0f);
    f16x8 hb[4];
#pragma unroll
    for (int kt = 0; kt < 4; ++kt) {
      hb[kt] = frag4(
          pack2(fmaf(-2.0f, th[8 * kt + 0], 1.0f), fmaf(-2.0f, th[8 * kt + 1], 1.0f)),
          pack2(fmaf(-2.0f, th[8 * kt + 2], 1.0f), fmaf(-2.0f, th[8 * kt + 3], 1.0f)),
          pack2(fmaf(-2.0f, th[8 * kt + 4], 1.0f), fmaf(-2.0f, th[8 * kt + 5], 1.0f)),
          pack2(fmaf(-2.0f, th[8 * kt + 6], 1.0f), fmaf(-2.0f, th[8 * kt + 7], 1.0f)));
    }
#pragma unroll
    for (int rt = 0; rt < 4; ++rt) {
      f32x4 tA = __builtin_amdgcn_mfma_f32_16x16x32_f16(wf2[rt][0], hb[0], b2C[rt], 0, 0, 0);
      tA = __builtin_amdgcn_mfma_f32_16x16x32_f16(wf2[rt][1], hb[1], tA, 0, 0, 0);
      f32x4 tB = __builtin_amdgcn_mfma_f32_16x16x32_f16(wf2[rt][2], hb[2], zf, 0, 0, 0);
      tB = __builtin_amdgcn_mfma_f32_16x16x32_f16(wf2[rt][3], hb[3], tB, 0, 0, 0);
      acc2[rt] = tA + tB;
    }
  };
#define FV(i) (acc2[(i) >> 2][(i) & 3])
  auto store_k = [&](int k) {
    if (!valid) return;
    const size_t base = (size_t)qpt * (ND * NTOUT);
#pragma unroll
    for (int mt = 0; mt < 4; ++mt) {
      const int d0 = 16 * mt + 4 * g;
      outg[base + (d0 + 0) * NTOUT + k] = y[4 * mt + 0];
      outg[base + (d0 + 1) * NTOUT + k] = y[4 * mt + 1];
      outg[base + (d0 + 2) * NTOUT + k] = y[4 * mt + 2];
      outg[base + (d0 + 3) * NTOUT + k] = y[4 * mt + 3];
    }
  };
  float tprev = tsg[b];
  store_k(0);
  mkyb(y);
#pragma unroll 1
  for (int k = 1; k < NTOUT; ++k) {
    float tnext = tsg[k * NB + b];
    float dt = tnext - tprev;
    int n = (int)ceilf(dt * 9.99f);
    n = n < 1 ? 1 : n;
    float h = dt / (float)n;
    float h2 = 0.5f * h, h6 = h * (1.0f / 6.0f), h3 = 2.0f * h6;
#pragma unroll 1
    for (int si = 0; si < n; ++si) {
#pragma unroll
      for (int i = 0; i < 16; ++i) y5[i] = y[i];
#pragma unroll 1
      for (int st = 0; st < 4; ++st) {
        feval();
        const float cB = (st == 0 || st == 3) ? h6 : h3;
#pragma unroll
        for (int i = 0; i < 16; ++i) y5[i] = fmaf(cB, FV(i), y5[i]);
        if (st < 3) {
          const float cA = (st == 2) ? h : h2;
          float yt[16];
#pragma unroll
          for (int i = 0; i < 16; ++i) yt[i] = fmaf(cA, FV(i), y[i]);
          mkyb(yt);
        } else {
#pragma unroll
          for (int i = 0; i < 16; ++i) y[i] = y5[i];
          mkyb(y);
        }
      }
    }
    store_k(k);
    tprev = tnext;
  }
#undef FV
}

extern "C" void kernel_launch(void* const* d_in, const int* in_sizes, int n_in,
                              void* d_out, int out_size, void* d_ws, size_t ws_size,
                              hipStream_t stream) {
  const float* y0 = (const float*)d_in[0];
  const float* ts = (const float*)d_in[1];
  const float* W1 = (const float*)d_in[2];
  const float* b1 = (const float*)d_in[3];
  const float* W2 = (const float*)d_in[4];
  const float* b2 = (const float*)d_in[5];
  float* out = (float*)d_out;

  const size_t need = (size_t)NB * NPT * NTOUT * 256;  // 127.8 MB records
  if (ws_size >= need) {
    unsigned* wsu = (unsigned*)d_ws;
    hipLaunchKernelGGL(node_rec_kernel, dim3(NTASK), dim3(64), 0, stream,
                       y0, ts, W1, b1, W2, b2, wsu);
    hipLaunchKernelGGL(hermite_out_kernel, dim3(NB * NCHUNK), dim3(256), 0,
                       stream, y0, ts, wsu, out);
  } else {
    hipLaunchKernelGGL(node_direct_kernel, dim3(NTASK), dim3(64), 0, stream,
                       y0, ts, W1, b1, W2, b2, out);
  }
}

// Round 20
// 131.731 us; speedup vs baseline: 1.2604x; 1.2604x over previous
//
#include <hip/hip_runtime.h>

// Neural-ODE, f(y) = tanh(y@W1+b1)@W2 + b2, 20800 independent 64-dim points.
// R20 = consolidation: kernel1 from R19 (SEG_CAP 0.25 + split MFMA chains,
// spill-free rolled RK4 recorder) + kernel2 from R18 (24KB-LDS Hermite
// expander, 73% occupancy, direct float4 stores) — R19's ybuf staging
// (lever 3) regressed occupancy 73->30% and is reverted.
// Structure (R15-R19 proven): recorder writes f16 {y0,f0} per merged
// segment to ws; expander rebuilds the segment map (identical FP logic)
// and cubic-Hermite-evaluates all 24 outputs per point.
// Per-feval machinery R8-R10-verified (zero-shuffle pi-permuted MFMA).

#define NB 64
#define NPT 325
#define ND 64
#define NH 128
#define NTOUT 24
#define GP16 21                   // ceil(325/16)
#define NTASK (NB * GP16)         // 1344 single-wave blocks
#define SEG_CAP 0.25f             // max RK4 step span (dt in [0.01,0.1])
#define CHUNK 4
#define NCHUNK ((NPT + CHUNK - 1) / CHUNK)   // 82

using f16x8 = __attribute__((ext_vector_type(8))) _Float16;
using f16x2 = __attribute__((ext_vector_type(2))) _Float16;
using f32x4 = __attribute__((ext_vector_type(4))) float;
using u32x4 = __attribute__((ext_vector_type(4))) unsigned;

__device__ __forceinline__ unsigned pack2(float lo, float hi) {
  auto pk = __builtin_amdgcn_cvt_pkrtz(lo, hi);
  return __builtin_bit_cast(unsigned, pk);
}

__device__ __forceinline__ f16x8 frag4(unsigned a, unsigned b, unsigned c, unsigned d) {
  u32x4 u = {a, b, c, d};
  return __builtin_bit_cast(f16x8, u);
}

__device__ __forceinline__ float h16(unsigned u, int hi) {
  f16x2 h = __builtin_bit_cast(f16x2, u);
  return (float)h[hi];
}

// ============================ kernel 1 (R19 verbatim) =======================
__global__ __launch_bounds__(64, 2) void node_rec_kernel(
    const float* __restrict__ y0g, const float* __restrict__ tsg,
    const float* __restrict__ W1g, const float* __restrict__ b1g,
    const float* __restrict__ W2g, const float* __restrict__ b2g,
    unsigned* __restrict__ wsu) {
  const int lane = threadIdx.x & 63;
  const int c = lane & 15;
  const int g = lane >> 4;

  const int task = blockIdx.x;
  const int b = task / GP16;
  const int p0 = (task - b * GP16) * 16;

  const float SC = 2.885390081777927f;  // 2*log2(e), folded into W1/b1

  f16x8 wf1[8][2];
#pragma unroll
  for (int rt = 0; rt < 8; ++rt)
#pragma unroll
    for (int kt = 0; kt < 2; ++kt) {
      f16x8 a;
#pragma unroll
      for (int j = 0; j < 8; ++j) {
        int ek = 4 * g + (j & 3) + ((j >> 2) << 4);
        a[j] = (_Float16)(W1g[(32 * kt + ek) * NH + 16 * rt + c] * SC);
      }
      wf1[rt][kt] = a;
    }
  f16x8 wf2[4][4];
#pragma unroll
  for (int rt = 0; rt < 4; ++rt)
#pragma unroll
    for (int kt = 0; kt < 4; ++kt) {
      f16x8 a;
#pragma unroll
      for (int j = 0; j < 8; ++j) {
        int ek = 4 * g + (j & 3) + ((j >> 2) << 4);
        a[j] = (_Float16)W2g[(32 * kt + ek) * ND + 16 * rt + c];
      }
      wf2[rt][kt] = a;
    }

  f32x4 b1C[8], b2C[4];
#pragma unroll
  for (int rt = 0; rt < 8; ++rt)
#pragma unroll
    for (int q = 0; q < 4; ++q) b1C[rt][q] = b1g[16 * rt + 4 * g + q] * SC;
#pragma unroll
  for (int rt = 0; rt < 4; ++rt)
#pragma unroll
    for (int q = 0; q < 4; ++q) b2C[rt][q] = b2g[16 * rt + 4 * g + q];

  const int ptc = p0 + c;
  const int qpt = b * NPT + min(ptc, NPT - 1);
  // clamped lanes duplicate the last point bitwise-identically (benign dups)

  float y[16], y5[16];
#pragma unroll
  for (int mt = 0; mt < 4; ++mt) {
    float4 v = *(const float4*)&y0g[qpt * ND + 16 * mt + 4 * g];
    y[4 * mt + 0] = v.x; y[4 * mt + 1] = v.y;
    y[4 * mt + 2] = v.z; y[4 * mt + 3] = v.w;
  }

  f16x8 yb0, yb1;
  auto mkyb = [&](const float* v) {
    yb0 = frag4(pack2(v[0], v[1]), pack2(v[2], v[3]),
                pack2(v[4], v[5]), pack2(v[6], v[7]));
    yb1 = frag4(pack2(v[8], v[9]), pack2(v[10], v[11]),
                pack2(v[12], v[13]), pack2(v[14], v[15]));
  };

  const f32x4 zf = {0.0f, 0.0f, 0.0f, 0.0f};
  f32x4 acc2[4];
  auto feval = [&]() {
    // layer 1: two INDEPENDENT MFMAs per row-tile + f32 add (1 MFMA latency)
    f32x4 acc[8];
#pragma unroll
    for (int rt = 0; rt < 8; ++rt) {
      f32x4 tA = __builtin_amdgcn_mfma_f32_16x16x32_f16(wf1[rt][0], yb0, b1C[rt], 0, 0, 0);
      f32x4 tB = __builtin_amdgcn_mfma_f32_16x16x32_f16(wf1[rt][1], yb1, zf, 0, 0, 0);
      acc[rt] = tA + tB;
    }
    float th[32];
#pragma unroll
    for (int i = 0; i < 32; ++i) th[i] = __builtin_exp2f(acc[i >> 2][i & 3]);
#pragma unroll
    for (int i = 0; i < 32; ++i) th[i] = __builtin_amdgcn_rcpf(th[i] + 1.0f);
    f16x8 hb[4];
#pragma unroll
    for (int kt = 0; kt < 4; ++kt) {
      hb[kt] = frag4(
          pack2(fmaf(-2.0f, th[8 * kt + 0], 1.0f), fmaf(-2.0f, th[8 * kt + 1], 1.0f)),
          pack2(fmaf(-2.0f, th[8 * kt + 2], 1.0f), fmaf(-2.0f, th[8 * kt + 3], 1.0f)),
          pack2(fmaf(-2.0f, th[8 * kt + 4], 1.0f), fmaf(-2.0f, th[8 * kt + 5], 1.0f)),
          pack2(fmaf(-2.0f, th[8 * kt + 6], 1.0f), fmaf(-2.0f, th[8 * kt + 7], 1.0f)));
    }
    // layer 2: 2x2-chain + add (2 MFMA latencies instead of 4)
#pragma unroll
    for (int rt = 0; rt < 4; ++rt) {
      f32x4 tA = __builtin_amdgcn_mfma_f32_16x16x32_f16(wf2[rt][0], hb[0], b2C[rt], 0, 0, 0);
      tA = __builtin_amdgcn_mfma_f32_16x16x32_f16(wf2[rt][1], hb[1], tA, 0, 0, 0);
      f32x4 tB = __builtin_amdgcn_mfma_f32_16x16x32_f16(wf2[rt][2], hb[2], zf, 0, 0, 0);
      tB = __builtin_amdgcn_mfma_f32_16x16x32_f16(wf2[rt][3], hb[3], tB, 0, 0, 0);
      acc2[rt] = tA + tB;
    }
  };

#define FV(i) (acc2[(i) >> 2][(i) & 3])

  const unsigned rbase = (unsigned)qpt * 1536u;
  auto store_rec = [&](int s) {  // record = {y0[64] f16, f0[64] f16}
    const unsigned o = rbase + (unsigned)s * 64u + 2u * g;
#pragma unroll
    for (int mt = 0; mt < 4; ++mt) {
      uint2 uy = make_uint2(pack2(y[4 * mt], y[4 * mt + 1]),
                            pack2(y[4 * mt + 2], y[4 * mt + 3]));
      *(uint2*)&wsu[o + 8u * mt] = uy;
      uint2 uf = make_uint2(pack2(FV(4 * mt), FV(4 * mt + 1)),
                            pack2(FV(4 * mt + 2), FV(4 * mt + 3)));
      *(uint2*)&wsu[o + 32u + 8u * mt] = uf;
    }
  };

  float t0 = tsg[b];
  mkyb(y);

  int s = 0;
  int k = 1;
#pragma unroll 1
  while (k < NTOUT) {
    int kend = k;
    float tend = tsg[k * NB + b];
#pragma unroll 1
    while (kend + 1 < NTOUT) {
      float tn = tsg[(kend + 1) * NB + b];
      if (tn - t0 <= SEG_CAP) { kend = kend + 1; tend = tn; } else break;
    }
    const float H = tend - t0;
    const float H2 = 0.5f * H;
    const float H6 = H * (1.0f / 6.0f);
    const float H3 = 2.0f * H6;

#pragma unroll
    for (int i = 0; i < 16; ++i) y5[i] = y[i];

#pragma unroll 1
    for (int st = 0; st < 4; ++st) {  // rolled stage loop (spill-free shape)
      feval();
      if (st == 0) store_rec(s);  // uniform branch: {y0, k1}
      const float cB = (st == 0 || st == 3) ? H6 : H3;
#pragma unroll
      for (int i = 0; i < 16; ++i) y5[i] = fmaf(cB, FV(i), y5[i]);
      if (st < 3) {
        const float cA = (st == 2) ? H : H2;
        float yt[16];
#pragma unroll
        for (int i = 0; i < 16; ++i) yt[i] = fmaf(cA, FV(i), y[i]);
        mkyb(yt);
      } else {
#pragma unroll
        for (int i = 0; i < 16; ++i) y[i] = y5[i];
        mkyb(y);
      }
    }
    s++;
    t0 = tend;
    k = kend + 1;
  }
  feval();
  store_rec(s);  // final {y_end, f_end}
#undef FV
}

// ============================ kernel 2 (R18 verbatim) =======================
// Block = 4 points of one batch; wave = point, lane = dim d.
__global__ __launch_bounds__(256) void hermite_out_kernel(
    const float* __restrict__ y0g, const float* __restrict__ tsg,
    const unsigned* __restrict__ wsu, float* __restrict__ outg) {
  __shared__ float ts_s[NTOUT];
  __shared__ float c0s[NTOUT], c1s[NTOUT], c2s[NTOUT], c3s[NTOUT];
  __shared__ int sidx[NTOUT];
  __shared__ int nseg_s;
  __shared__ unsigned recs[CHUNK][NTOUT * 64];  // 24 KB: 4 pts x 24 recs

  const int tid = threadIdx.x;
  const int b = blockIdx.x / NCHUNK;
  const int chunk = blockIdx.x - b * NCHUNK;
  const int pbase = chunk * CHUNK;

  if (tid < NTOUT) ts_s[tid] = tsg[tid * NB + b];
  __syncthreads();

  if (tid == 0) {  // identical FP logic to kernel1's merge
    float t0 = ts_s[0];
    int s = 0, k = 1;
    while (k < NTOUT) {
      int kend = k;
      float tend = ts_s[k];
      while (kend + 1 < NTOUT) {
        float tn = ts_s[kend + 1];
        if (tn - t0 <= SEG_CAP) { kend = kend + 1; tend = tn; } else break;
      }
      float H = tend - t0;
      for (int kk = k; kk <= kend; ++kk) {
        float th = (ts_s[kk] - t0) / H;
        float th2 = th * th, th3 = th2 * th;
        c0s[kk] = 2.0f * th3 - 3.0f * th2 + 1.0f;
        c1s[kk] = (th3 - 2.0f * th2 + th) * H;
        c2s[kk] = 3.0f * th2 - 2.0f * th3;
        c3s[kk] = (th3 - th2) * H;
        sidx[kk] = s;
      }
      s++;
      t0 = tend;
      k = kend + 1;
    }
    nseg_s = s;
  }
  __syncthreads();

  // stage records for the 4 points (coalesced uint4 loads, linear LDS)
  const int nr4 = (nseg_s + 1) * 16;  // uint4 per point
#pragma unroll 1
  for (int p = 0; p < CHUNK; ++p) {
    const int q = b * NPT + min(pbase + p, NPT - 1);
    const u32x4* src = (const u32x4*)(wsu + (size_t)q * 1536u);
#pragma unroll 1
    for (int i = tid; i < nr4; i += 256)
      *(u32x4*)&recs[p][i * 4] = src[i];
  }
  __syncthreads();

  // wave w handles point pbase + w; lane = dim d
  const int w = tid >> 6;
  const int lane = tid & 63;
  const int pt = pbase + w;
  const bool valid = pt < NPT;
  const int q = b * NPT + min(pt, NPT - 1);
  const int dw = lane >> 1, hi = lane & 1;
  float* orow = outg + (size_t)q * (ND * NTOUT) + lane * NTOUT;

  const float o0 = y0g[q * ND + lane];  // exact k=0

  float y0v = 0.f, f0v = 0.f, y1v = 0.f, f1v = 0.f;
  int cur = -1;
#pragma unroll 1
  for (int kc = 0; kc < 6; ++kc) {
    float vals[4];
#pragma unroll
    for (int j = 0; j < 4; ++j) {
      const int k = kc * 4 + j;
      if (kc == 0 && j == 0) {
        vals[0] = o0;
        continue;
      }
      const int s = sidx[k];     // uniform across wave
      if (s != cur) {            // uniform branch; few reloads per point
        cur = s;
        y0v = h16(recs[w][s * 64 + dw], hi);
        f0v = h16(recs[w][s * 64 + 32 + dw], hi);
        y1v = h16(recs[w][(s + 1) * 64 + dw], hi);
        f1v = h16(recs[w][(s + 1) * 64 + 32 + dw], hi);
      }
      vals[j] = fmaf(c0s[k], y0v,
                fmaf(c1s[k], f0v,
                fmaf(c2s[k], y1v, c3s[k] * f1v)));
    }
    if (valid)
      *(float4*)&orow[kc * 4] = make_float4(vals[0], vals[1], vals[2], vals[3]);
  }
}

// ====================== fallback (ws too small; never expected) =============
__global__ __launch_bounds__(64, 2) void node_direct_kernel(
    const float* __restrict__ y0g, const float* __restrict__ tsg,
    const float* __restrict__ W1g, const float* __restrict__ b1g,
    const float* __restrict__ W2g, const float* __restrict__ b2g,
    float* __restrict__ outg) {
  const int lane = threadIdx.x & 63;
  const int c = lane & 15;
  const int g = lane >> 4;
  const int task = blockIdx.x;
  const int b = task / GP16;
  const int p0 = (task - b * GP16) * 16;
  const float SC = 2.885390081777927f;

  f16x8 wf1[8][2];
#pragma unroll
  for (int rt = 0; rt < 8; ++rt)
#pragma unroll
    for (int kt = 0; kt < 2; ++kt) {
      f16x8 a;
#pragma unroll
      for (int j = 0; j < 8; ++j) {
        int ek = 4 * g + (j & 3) + ((j >> 2) << 4);
        a[j] = (_Float16)(W1g[(32 * kt + ek) * NH + 16 * rt + c] * SC);
      }
      wf1[rt][kt] = a;
    }
  f16x8 wf2[4][4];
#pragma unroll
  for (int rt = 0; rt < 4; ++rt)
#pragma unroll
    for (int kt = 0; kt < 4; ++kt) {
      f16x8 a;
#pragma unroll
      for (int j = 0; j < 8; ++j) {
        int ek = 4 * g + (j & 3) + ((j >> 2) << 4);
        a[j] = (_Float16)W2g[(32 * kt + ek) * ND + 16 * rt + c];
      }
      wf2[rt][kt] = a;
    }
  f32x4 b1C[8], b2C[4];
#pragma unroll
  for (int rt = 0; rt < 8; ++rt)
#pragma unroll
    for (int q = 0; q < 4; ++q) b1C[rt][q] = b1g[16 * rt + 4 * g + q] * SC;
#pragma unroll
  for (int rt = 0; rt < 4; ++rt)
#pragma unroll
    for (int q = 0; q < 4; ++q) b2C[rt][q] = b2g[16 * rt + 4 * g + q];

  const int ptc = p0 + c;
  const bool valid = ptc < NPT;
  const int qpt = b * NPT + min(ptc, NPT - 1);
  float y[16], y5[16];
#pragma unroll
  for (int mt = 0; mt < 4; ++mt) {
    float4 v = *(const float4*)&y0g[qpt * ND + 16 * mt + 4 * g];
    y[4 * mt + 0] = v.x; y[4 * mt + 1] = v.y;
    y[4 * mt + 2] = v.z; y[4 * mt + 3] = v.w;
  }
  f16x8 yb0, yb1;
  auto mkyb = [&](const float* v) {
    yb0 = frag4(pack2(v[0], v[1]), pack2(v[2], v[3]),
                pack2(v[4], v[5]), pack2(v[6], v[7]));
    yb1 = frag4(pack2(v[8], v[9]), pack2(v[10], v[11]),
                pack2(v[12], v[13]), pack2(v[14], v[15]));
  };
  const f32x4 zf = {0.0f, 0.0f, 0.0f, 0.0f};
  f32x4 acc2[4];
  auto feval = [&]() {
    f32x4 acc[8];
#pragma unroll
    for (int rt = 0; rt < 8; ++rt) {
      f32x4 tA = __builtin_amdgcn_mfma_f32_16x16x32_f16(wf1[rt][0], yb0, b1C[rt], 0, 0, 0);
      f32x4 tB = __builtin_amdgcn_mfma_f32_16x16x32_f16(wf1[rt][1], yb1, zf, 0, 0, 0);
      acc[rt] = tA + tB;
    }
    float th[32];
#pragma unroll
    for (int i = 0; i < 32; ++i) th[i] = __builtin_exp2f(acc[i >> 2][i & 3]);
#pragma unroll
    for (int i = 0; i < 32; ++i) th[i] = __builtin_amdgcn_rcpf(th[i] + 1.0f);
    f16x8 hb[4];
#pragma unroll
    for (int kt = 0; kt < 4; ++kt) {
      hb[kt] = frag4(
          pack2(fmaf(-2.0f, th[8 * kt + 0], 1.0f), fmaf(-2.0f, th[8 * kt + 1], 1.0f)),
          pack2(fmaf(-2.0f, th[8 * kt + 2], 1.0f), fmaf(-2.0f, th[8 * kt + 3], 1.0f)),
          pack2(fmaf(-2.0f, th[8 * kt + 4], 1.0f), fmaf(-2.0f, th[8 * kt + 5], 1.0f)),
          pack2(fmaf(-2.0f, th[8 * kt + 6], 1.0f), fmaf(-2.0f, th[8 * kt + 7], 1.0f)));
    }
#pragma unroll
    for (int rt = 0; rt < 4; ++rt) {
      f32x4 tA = __builtin_amdgcn_mfma_f32_16x16x32_f16(wf2[rt][0], hb[0], b2C[rt], 0, 0, 0);
      tA = __builtin_amdgcn_mfma_f32_16x16x32_f16(wf2[rt][1], hb[1], tA, 0, 0, 0);
      f32x4 tB = __builtin_amdgcn_mfma_f32_16x16x32_f16(wf2[rt][2], hb[2], zf, 0, 0, 0);
      tB = __builtin_amdgcn_mfma_f32_16x16x32_f16(wf2[rt][3], hb[3], tB, 0, 0, 0);
      acc2[rt] = tA + tB;
    }
  };
#define FV(i) (acc2[(i) >> 2][(i) & 3])
  auto store_k = [&](int k) {
    if (!valid) return;
    const size_t base = (size_t)qpt * (ND * NTOUT);
#pragma unroll
    for (int mt = 0; mt < 4; ++mt) {
      const int d0 = 16 * mt + 4 * g;
      outg[base + (d0 + 0) * NTOUT + k] = y[4 * mt + 0];
      outg[base + (d0 + 1) * NTOUT + k] = y[4 * mt + 1];
      outg[base + (d0 + 2) * NTOUT + k] = y[4 * mt + 2];
      outg[base + (d0 + 3) * NTOUT + k] = y[4 * mt + 3];
    }
  };
  float tprev = tsg[b];
  store_k(0);
  mkyb(y);
#pragma unroll 1
  for (int k = 1; k < NTOUT; ++k) {
    float tnext = tsg[k * NB + b];
    float dt = tnext - tprev;
    int n = (int)ceilf(dt * 9.99f);
    n = n < 1 ? 1 : n;
    float h = dt / (float)n;
    float h2 = 0.5f * h, h6 = h * (1.0f / 6.0f), h3 = 2.0f * h6;
#pragma unroll 1
    for (int si = 0; si < n; ++si) {
#pragma unroll
      for (int i = 0; i < 16; ++i) y5[i] = y[i];
#pragma unroll 1
      for (int st = 0; st < 4; ++st) {
        feval();
        const float cB = (st == 0 || st == 3) ? h6 : h3;
#pragma unroll
        for (int i = 0; i < 16; ++i) y5[i] = fmaf(cB, FV(i), y5[i]);
        if (st < 3) {
          const float cA = (st == 2) ? h : h2;
          float yt[16];
#pragma unroll
          for (int i = 0; i < 16; ++i) yt[i] = fmaf(cA, FV(i), y[i]);
          mkyb(yt);
        } else {
#pragma unroll
          for (int i = 0; i < 16; ++i) y[i] = y5[i];
          mkyb(y);
        }
      }
    }
    store_k(k);
    tprev = tnext;
  }
#undef FV
}

extern "C" void kernel_launch(void* const* d_in, const int* in_sizes, int n_in,
                              void* d_out, int out_size, void* d_ws, size_t ws_size,
                              hipStream_t stream) {
  const float* y0 = (const float*)d_in[0];
  const float* ts = (const float*)d_in[1];
  const float* W1 = (const float*)d_in[2];
  const float* b1 = (const float*)d_in[3];
  const float* W2 = (const float*)d_in[4];
  const float* b2 = (const float*)d_in[5];
  float* out = (float*)d_out;

  const size_t need = (size_t)NB * NPT * NTOUT * 256;  // 127.8 MB records
  if (ws_size >= need) {
    unsigned* wsu = (unsigned*)d_ws;
    hipLaunchKernelGGL(node_rec_kernel, dim3(NTASK), dim3(64), 0, stream,
                       y0, ts, W1, b1, W2, b2, wsu);
    hipLaunchKernelGGL(hermite_out_kernel, dim3(NB * NCHUNK), dim3(256), 0,
                       stream, y0, ts, wsu, out);
  } else {
    hipLaunchKernelGGL(node_direct_kernel, dim3(NTASK), dim3(64), 0, stream,
                       y0, ts, W1, b1, W2, b2, out);
  }
}